// Round 13
// baseline (1677.090 us; speedup 1.0000x reference)
//
#include <hip/hip_runtime.h>
#include <math.h>

#define Bn 8
#define Tn 2048
#define Dn 256
#define NTICK 3
#define NROWS (Bn*Tn)      // 16384
#define ABM 64             // attention Q-rows per block
#define NBLKA (NROWS/ABM)  // 256
#define BS 64              // KV tile
#define GM 64              // GEMM rows per block
#define NBLKG (NROWS/GM)   // 256
#define WP 65536           // weight plane elems (256*256)

typedef unsigned int u32;
typedef unsigned short u16;
typedef __attribute__((ext_vector_type(8))) short bf16x8;
typedef __attribute__((ext_vector_type(4))) float f32x4;
typedef __attribute__((ext_vector_type(16))) float f32x16;

__device__ __forceinline__ float bf2f(u32 u){
  union { u32 i; float f; } x; x.i = u << 16; return x.f;
}
__device__ __forceinline__ u16 f2bf(float f){
  union { float f; u32 i; } x; x.f = f;
  u32 r = (x.i + 0x7fffu + ((x.i >> 16) & 1u)) >> 16;
  return (u16)r;
}
// async global->LDS 16B: per-lane global src, wave-uniform LDS base + lane*16
__device__ __forceinline__ void gld_lds16(const u16* gsrc, u16* ldst){
  __builtin_amdgcn_global_load_lds(
      (const __attribute__((address_space(1))) u32*)(const void*)gsrc,
      (__attribute__((address_space(3))) u32*)(void*)ldst, 16, 0, 0);
}

// ======== GEMM building blocks ========
__device__ __forceinline__ void stage_A(const u16* __restrict__ A, int row0, char* smem){
  const int tid = threadIdx.x, lane = tid & 63, w = tid >> 6;
  #pragma unroll
  for (int r=0;r<8;++r){
    int s = w*16 + 2*r + (lane>>5);
    int slot = (lane & 31) ^ (s & 7);
    gld_lds16(A + (size_t)(row0 + s)*Dn + slot*8, (u16*)(smem + (w*16 + 2*r)*512));
  }
}
__device__ __forceinline__ void load_frags(const char* smem, bf16x8* af){
  const int tid = threadIdx.x, lane = tid & 63, w = tid >> 6;
  const int l7 = lane & 7, g = (lane >> 4) & 3, q15 = lane & 15;
  const char* ab = smem + (w*16 + q15)*512;
  #pragma unroll
  for (int kk=0;kk<8;++kk) af[kk] = *(const bf16x8*)(ab + 16*((4*kk+g)^l7));
}
// stage one 16-row W chunk (8KB) block-cooperatively (2 gld/thread), stage_A swizzle
__device__ __forceinline__ void stage_Wchunk(const u16* __restrict__ W, int c, char* wbuf){
  const int tid = threadIdx.x, lane = tid & 63, w = tid >> 6;
  #pragma unroll
  for (int r=0;r<2;++r){
    int rl = w*4 + 2*r + (lane>>5);
    int slot = (lane & 31) ^ (rl & 7);
    gld_lds16(W + (size_t)(c*16 + rl)*Dn + slot*8, (u16*)(wbuf + (w*4 + 2*r)*512));
  }
}
__device__ __forceinline__ void load_wfrags(const char* wbuf, bf16x8* wf){
  const int lane = threadIdx.x & 63;
  const int l7 = lane & 7, g = (lane >> 4) & 3, q15 = lane & 15;
  const char* wb_ = wbuf + q15*512;
  #pragma unroll
  for (int kk=0;kk<8;++kk) wf[kk] = *(const bf16x8*)(wb_ + 16*((4*kk+g)^l7));
}
__device__ __forceinline__ void zero_acc(f32x4* acc){
  #pragma unroll
  for (int nt=0;nt<16;++nt) acc[nt] = (f32x4){0.f,0.f,0.f,0.f};
}
#define CHUNK_STEP(c, NC, PLANE_OF, IDX_OF)                                    \
  asm volatile("s_waitcnt lgkmcnt(0)" ::: "memory");                           \
  if ((c) < (NC)-2) { asm volatile("s_waitcnt vmcnt(2)" ::: "memory"); }       \
  else              { asm volatile("s_waitcnt vmcnt(0)" ::: "memory"); }       \
  __builtin_amdgcn_sched_barrier(0);                                           \
  __builtin_amdgcn_s_barrier();                                                \
  if ((c)+3 < (NC)) stage_Wchunk(PLANE_OF((c)+3), IDX_OF((c)+3), ring + (((c)+3)&3)*8192);

// ---------------- weights f32 -> (hi, lo) bf16 planes ----------------
__global__ void k_prep(const float* __restrict__ s0, const float* __restrict__ s1,
                       const float* __restrict__ s2, const float* __restrict__ s3,
                       const float* __restrict__ s4, const float* __restrict__ s5,
                       const float* __restrict__ s6, u16* __restrict__ dst){
  int y = blockIdx.y;
  const float* s = (y==0)?s0:(y==1)?s1:(y==2)?s2:(y==3)?s3:(y==4)?s4:(y==5)?s5:s6;
  int i = (blockIdx.x*256 + threadIdx.x)*4;
  float4 v = *(const float4*)(s + i);
  u16 h0=f2bf(v.x), h1=f2bf(v.y), h2=f2bf(v.z), h3=f2bf(v.w);
  uint2 hi, lo;
  hi.x = (u32)h0 | ((u32)h1 << 16);
  hi.y = (u32)h2 | ((u32)h3 << 16);
  lo.x = (u32)f2bf(v.x - bf2f(h0)) | ((u32)f2bf(v.y - bf2f(h1)) << 16);
  lo.y = (u32)f2bf(v.z - bf2f(h2)) | ((u32)f2bf(v.w - bf2f(h3)) << 16);
  *(uint2*)(dst + (size_t)y*WP + i) = hi;
  *(uint2*)(dst + (size_t)(7+y)*WP + i) = lo;
}

// ---------------- z f32 -> (hi, lo) ; also zero stats ----------------
__global__ void k_split(const float* __restrict__ s, u16* __restrict__ dh, u16* __restrict__ dl,
                        float* __restrict__ stats){
  if (blockIdx.x == 0 && threadIdx.x < 64) stats[threadIdx.x] = 0.f;
  int i = (blockIdx.x*256 + threadIdx.x)*4;
  float4 v = *(const float4*)(s + i);
  u16 h0=f2bf(v.x), h1=f2bf(v.y), h2=f2bf(v.z), h3=f2bf(v.w);
  uint2 hi, lo;
  hi.x = (u32)h0 | ((u32)h1 << 16);
  hi.y = (u32)h2 | ((u32)h3 << 16);
  lo.x = (u32)f2bf(v.x - bf2f(h0)) | ((u32)f2bf(v.y - bf2f(h1)) << 16);
  lo.y = (u32)f2bf(v.z - bf2f(h2)) | ((u32)f2bf(v.w - bf2f(h3)) << 16);
  *(uint2*)(dh + i) = hi;
  *(uint2*)(dl + i) = lo;
}

// ---------------- h = LN(z @ in_w^T + in_b) * g + beta -> bf16 (split z, split W) ----------------
__global__ __launch_bounds__(256) void k_gemm_ln(
    const u16* __restrict__ Ahi, const u16* __restrict__ Alo,
    const u16* __restrict__ Whi, const u16* __restrict__ Wlo,
    const float* __restrict__ bias, const float* __restrict__ gamma, const float* __restrict__ beta,
    u16* __restrict__ h)
{
  __shared__ __align__(16) char smem[65536];
  char* ring = smem;
  f32x4 acc[16];
  const int row0 = blockIdx.x * GM;
  stage_A(Ahi, row0, smem);
  stage_A(Alo, row0, smem + 32768);
  asm volatile("s_waitcnt vmcnt(0)" ::: "memory");
  __builtin_amdgcn_sched_barrier(0);
  bf16x8 afh[8], afl[8];
  load_frags(smem, afh);
  load_frags(smem + 32768, afl);
  asm volatile("s_waitcnt lgkmcnt(0)" ::: "memory");
  __builtin_amdgcn_sched_barrier(0);
  __builtin_amdgcn_s_barrier();
  zero_acc(acc);
  #define LN_PL(i) ((i) < 16 ? Whi : Wlo)
  #define LN_IX(i) ((i) & 15)
  stage_Wchunk(LN_PL(0), LN_IX(0), ring + 0*8192);
  stage_Wchunk(LN_PL(1), LN_IX(1), ring + 1*8192);
  stage_Wchunk(LN_PL(2), LN_IX(2), ring + 2*8192);
  asm volatile("s_waitcnt vmcnt(4)" ::: "memory");
  __builtin_amdgcn_sched_barrier(0);
  __builtin_amdgcn_s_barrier();
  for (int c=0; c<32; ++c){
    bf16x8 wf[8];
    load_wfrags(ring + (c&3)*8192, wf);
    int nt = c & 15;
    if (c < 16){
      #pragma unroll
      for (int kk=0;kk<8;++kk)
        acc[nt] = __builtin_amdgcn_mfma_f32_16x16x32_bf16(afh[kk], wf[kk], acc[nt], 0,0,0);
      #pragma unroll
      for (int kk=0;kk<8;++kk)
        acc[nt] = __builtin_amdgcn_mfma_f32_16x16x32_bf16(afl[kk], wf[kk], acc[nt], 0,0,0);
    } else {
      #pragma unroll
      for (int kk=0;kk<8;++kk)
        acc[nt] = __builtin_amdgcn_mfma_f32_16x16x32_bf16(afh[kk], wf[kk], acc[nt], 0,0,0);
    }
    CHUNK_STEP(c, 32, LN_PL, LN_IX)
  }
  const int tid = threadIdx.x, lane = tid & 63, w = tid >> 6;
  const int g4 = lane >> 4, q15 = lane & 15;
  float bcol[16], gcol[16], becol[16];
  #pragma unroll
  for (int nt=0;nt<16;++nt){
    int col = nt*16 + q15;
    bcol[nt] = bias[col]; gcol[nt] = gamma[col]; becol[nt] = beta[col];
  }
  float mu[4], rstd[4];
  #pragma unroll
  for (int j=0;j<4;++j){
    float s=0.f, q=0.f;
    #pragma unroll
    for (int nt=0;nt<16;++nt){ float v = acc[nt][j] + bcol[nt]; s += v; q += v*v; }
    #pragma unroll
    for (int off=1; off<16; off<<=1){ s += __shfl_xor(s,off); q += __shfl_xor(q,off); }
    float m = s*(1.f/Dn);
    mu[j] = m; rstd[j] = rsqrtf(q*(1.f/Dn) - m*m + 1e-5f);
  }
  const size_t rbase = (size_t)(row0 + w*16 + g4*4);
  #pragma unroll
  for (int nt=0;nt<16;++nt){
    #pragma unroll
    for (int j=0;j<4;++j){
      float v = (acc[nt][j] + bcol[nt] - mu[j])*rstd[j]*gcol[nt] + becol[nt];
      h[(rbase+j)*Dn + nt*16 + q15] = f2bf(v);
    }
  }
}

// ---------------- Q/K/V = h @ w^T + b -> bf16 (split W, 3-dispatch) ----------------
__global__ __launch_bounds__(256) void k_gemm_qkv(
    const u16* __restrict__ h, const u16* __restrict__ wbf,
    const float* __restrict__ qb, const float* __restrict__ kb, const float* __restrict__ vb,
    u16* __restrict__ Qo, u16* __restrict__ Ko, u16* __restrict__ Vo)
{
  const u16 *Whi, *Wlo; const float* bias; u16* out;
  if (blockIdx.y == 0){ Whi = wbf + 1*WP; Wlo = wbf + 8*WP;  bias = qb; out = Qo; }
  else if (blockIdx.y == 1){ Whi = wbf + 2*WP; Wlo = wbf + 9*WP;  bias = kb; out = Ko; }
  else { Whi = wbf + 3*WP; Wlo = wbf + 10*WP; bias = vb; out = Vo; }
  __shared__ __align__(16) char smem[65536];
  char* ring = smem + 32768;
  f32x4 acc[16];
  const int row0 = blockIdx.x * GM;
  stage_A(h, row0, smem);
  #define QK_PL(i) ((i) < 16 ? Whi : Wlo)
  #define QK_IX(i) ((i) & 15)
  stage_Wchunk(QK_PL(0), QK_IX(0), ring + 0*8192);
  stage_Wchunk(QK_PL(1), QK_IX(1), ring + 1*8192);
  stage_Wchunk(QK_PL(2), QK_IX(2), ring + 2*8192);
  asm volatile("s_waitcnt vmcnt(4)" ::: "memory");   // A + chunk0 (mine) done
  __builtin_amdgcn_sched_barrier(0);
  bf16x8 af[8];
  load_frags(smem, af);
  zero_acc(acc);
  __builtin_amdgcn_s_barrier();                      // chunk0 staged (all)
  for (int c=0; c<32; ++c){
    bf16x8 wf[8];
    load_wfrags(ring + (c&3)*8192, wf);
    int nt = c & 15;
    #pragma unroll
    for (int kk=0;kk<8;++kk)
      acc[nt] = __builtin_amdgcn_mfma_f32_16x16x32_bf16(af[kk], wf[kk], acc[nt], 0,0,0);
    CHUNK_STEP(c, 32, QK_PL, QK_IX)
  }
  const int tid = threadIdx.x, lane = tid & 63, w = tid >> 6;
  const int g4 = lane >> 4, q15 = lane & 15;
  const size_t rbase = (size_t)(row0 + w*16 + g4*4);
  #pragma unroll
  for (int nt=0;nt<16;++nt){
    float bc = bias[nt*16 + q15];
    #pragma unroll
    for (int j=0;j<4;++j)
      out[(rbase+j)*Dn + nt*16 + q15] = f2bf(acc[nt][j] + bc);
  }
}

// ---------------- update: z_new = z + ((ctx @ o_w^T + o_b) - z)/(tau+1e-6) ----------------
__global__ __launch_bounds__(256) void k_gemm_update(
    const u16* __restrict__ Chi, const u16* __restrict__ Clo,
    const u16* __restrict__ Whi, const u16* __restrict__ Wlo,
    const float* __restrict__ ob,
    const u16* __restrict__ zhi_old, const u16* __restrict__ zlo_old,
    const float* __restrict__ log_tau,
    u16* __restrict__ zhi_new, u16* __restrict__ zlo_new,
    float* __restrict__ zout)
{
  __shared__ __align__(16) char smem[65536];
  char* ring = smem;
  f32x4 acc[16];
  const int row0 = blockIdx.x * GM;
  stage_A(Chi, row0, smem);
  stage_A(Clo, row0, smem + 32768);
  asm volatile("s_waitcnt vmcnt(0)" ::: "memory");
  __builtin_amdgcn_sched_barrier(0);
  bf16x8 afh[8], afl[8];
  load_frags(smem, afh);
  load_frags(smem + 32768, afl);
  asm volatile("s_waitcnt lgkmcnt(0)" ::: "memory");
  __builtin_amdgcn_sched_barrier(0);
  __builtin_amdgcn_s_barrier();
  zero_acc(acc);
  stage_Wchunk(LN_PL(0), LN_IX(0), ring + 0*8192);
  stage_Wchunk(LN_PL(1), LN_IX(1), ring + 1*8192);
  stage_Wchunk(LN_PL(2), LN_IX(2), ring + 2*8192);
  asm volatile("s_waitcnt vmcnt(4)" ::: "memory");
  __builtin_amdgcn_sched_barrier(0);
  __builtin_amdgcn_s_barrier();
  for (int c=0; c<32; ++c){
    bf16x8 wf[8];
    load_wfrags(ring + (c&3)*8192, wf);
    int nt = c & 15;
    if (c < 16){
      #pragma unroll
      for (int kk=0;kk<8;++kk)
        acc[nt] = __builtin_amdgcn_mfma_f32_16x16x32_bf16(afh[kk], wf[kk], acc[nt], 0,0,0);
      #pragma unroll
      for (int kk=0;kk<8;++kk)
        acc[nt] = __builtin_amdgcn_mfma_f32_16x16x32_bf16(afl[kk], wf[kk], acc[nt], 0,0,0);
    } else {
      #pragma unroll
      for (int kk=0;kk<8;++kk)
        acc[nt] = __builtin_amdgcn_mfma_f32_16x16x32_bf16(afh[kk], wf[kk], acc[nt], 0,0,0);
    }
    CHUNK_STEP(c, 32, LN_PL, LN_IX)
  }
  const int tid = threadIdx.x, lane = tid & 63, w = tid >> 6;
  const int g4 = lane >> 4, q15 = lane & 15;
  const size_t rbase = (size_t)(row0 + w*16 + g4*4);
  #pragma unroll
  for (int nt=0;nt<16;++nt){
    int col = nt*16 + q15;
    float bc = ob[col];
    float invt = 1.f/(expf(log_tau[col]) + 1e-6f);
    #pragma unroll
    for (int j=0;j<4;++j){
      size_t idx = (rbase+j)*Dn + col;
      float zo = bf2f(zhi_old[idx]) + bf2f(zlo_old[idx]);
      float zn = zo + (acc[nt][j] + bc - zo)*invt;
      u16 zh = f2bf(zn);
      zhi_new[idx] = zh;
      zlo_new[idx] = f2bf(zn - bf2f(zh));
      if (zout) zout[idx] = zn;
    }
  }
}

// ---------------- t1 = relu(zhi @ p1^T + b1) -> bf16 ----------------
__global__ __launch_bounds__(256) void k_gemm_relu(
    const u16* __restrict__ A, const u16* __restrict__ Wb, const float* __restrict__ bias,
    u16* __restrict__ t1)
{
  __shared__ __align__(16) char smem[65536];
  char* ring = smem + 32768;
  f32x4 acc[16];
  const int row0 = blockIdx.x * GM;
  stage_A(A, row0, smem);
  #define W1_PL(i) (Wb)
  #define W1_IX(i) (i)
  stage_Wchunk(Wb, 0, ring + 0*8192);
  stage_Wchunk(Wb, 1, ring + 1*8192);
  stage_Wchunk(Wb, 2, ring + 2*8192);
  asm volatile("s_waitcnt vmcnt(4)" ::: "memory");
  __builtin_amdgcn_sched_barrier(0);
  bf16x8 af[8];
  load_frags(smem, af);
  zero_acc(acc);
  __builtin_amdgcn_s_barrier();
  for (int c=0; c<16; ++c){
    bf16x8 wf[8];
    load_wfrags(ring + (c&3)*8192, wf);
    #pragma unroll
    for (int kk=0;kk<8;++kk)
      acc[c] = __builtin_amdgcn_mfma_f32_16x16x32_bf16(af[kk], wf[kk], acc[c], 0,0,0);
    CHUNK_STEP(c, 16, W1_PL, W1_IX)
  }
  const int tid = threadIdx.x, lane = tid & 63, w = tid >> 6;
  const int g4 = lane >> 4, q15 = lane & 15;
  const size_t rbase = (size_t)(row0 + w*16 + g4*4);
  #pragma unroll
  for (int nt=0;nt<16;++nt){
    float bc = bias[nt*16 + q15];
    #pragma unroll
    for (int j=0;j<4;++j)
      t1[(rbase+j)*Dn + nt*16 + q15] = f2bf(fmaxf(acc[nt][j] + bc, 0.f));
  }
}

// ---------------- loss += sum((t1 @ p2^T + b2 - z_new)^2) ----------------
__global__ __launch_bounds__(256) void k_gemm_loss(
    const u16* __restrict__ t1, const u16* __restrict__ Wb, const float* __restrict__ bias,
    const u16* __restrict__ zhi_new, const u16* __restrict__ zlo_new,
    float* __restrict__ loss_acc)
{
  __shared__ __align__(16) char smem[65536];
  __shared__ float red[4];
  char* ring = smem + 32768;
  f32x4 acc[16];
  const int row0 = blockIdx.x * GM;
  stage_A(t1, row0, smem);
  stage_Wchunk(Wb, 0, ring + 0*8192);
  stage_Wchunk(Wb, 1, ring + 1*8192);
  stage_Wchunk(Wb, 2, ring + 2*8192);
  asm volatile("s_waitcnt vmcnt(4)" ::: "memory");
  __builtin_amdgcn_sched_barrier(0);
  bf16x8 af[8];
  load_frags(smem, af);
  zero_acc(acc);
  __builtin_amdgcn_s_barrier();
  for (int c=0; c<16; ++c){
    bf16x8 wf[8];
    load_wfrags(ring + (c&3)*8192, wf);
    #pragma unroll
    for (int kk=0;kk<8;++kk)
      acc[c] = __builtin_amdgcn_mfma_f32_16x16x32_bf16(af[kk], wf[kk], acc[c], 0,0,0);
    CHUNK_STEP(c, 16, W1_PL, W1_IX)
  }
  const int tid = threadIdx.x, lane = tid & 63, w = tid >> 6;
  const int g4 = lane >> 4, q15 = lane & 15;
  const size_t rbase = (size_t)(row0 + w*16 + g4*4);
  float lsum = 0.f;
  #pragma unroll
  for (int nt=0;nt<16;++nt){
    float bc = bias[nt*16 + q15];
    #pragma unroll
    for (int j=0;j<4;++j){
      size_t idx = (rbase+j)*Dn + nt*16 + q15;
      float zn = bf2f(zhi_new[idx]) + bf2f(zlo_new[idx]);
      float dn = acc[nt][j] + bc - zn;
      lsum += dn*dn;
    }
  }
  #pragma unroll
  for (int off=1; off<64; off<<=1) lsum += __shfl_xor(lsum, off);
  if (lane == 0) red[w] = lsum;
  __syncthreads();
  if (tid == 0) atomicAdd(loss_acc, red[0]+red[1]+red[2]+red[3]);
}

// ---------------- pass A: 32x32 MFMA, K dbuf; also stores per-row max ----------------
__global__ __launch_bounds__(256) void k_passA(
    const u16* __restrict__ Qg, const u16* __restrict__ Kg,
    float* __restrict__ conf_b, float* __restrict__ mrow)
{
  __shared__ __align__(16) char smem[65536];
  const int tid = threadIdx.x;
  const int lane = tid & 63, w = tid >> 6;
  const int l31 = lane & 31, hi5 = lane >> 5;
  const int qh = w >> 1, sh = w & 1;
  const int row0 = blockIdx.x * ABM;
  const int b = row0 >> 11;
  const size_t kbase = (size_t)b * Tn * Dn;

  #pragma unroll
  for (int r=0;r<8;++r){
    int s = w*16 + 2*r + (lane>>5);
    int slot = (lane & 31) ^ (s & 7);
    gld_lds16(Qg + (size_t)(row0 + s)*Dn + slot*8, (u16*)(smem + (w*16 + 2*r)*512));
  }
  asm volatile("s_waitcnt vmcnt(0)" ::: "memory");
  __builtin_amdgcn_sched_barrier(0);
  __builtin_amdgcn_s_barrier();                      // Q visible to all
  bf16x8 qf[16];
  {
    const char* qb = smem + (qh*32 + l31)*512;
    const int r7 = l31 & 7;
    #pragma unroll
    for (int t=0;t<16;++t) qf[t] = *(const bf16x8*)(qb + 16*((2*t+hi5)^r7));
  }
  asm volatile("s_waitcnt lgkmcnt(0)" ::: "memory");
  __builtin_amdgcn_sched_barrier(0);
  __builtin_amdgcn_s_barrier();                      // all Q reads done
  #pragma unroll
  for (int r=0;r<8;++r){
    int s = w*16 + 2*r + (lane>>5);
    int slot = (lane & 31) ^ (s & 7);
    gld_lds16(Kg + kbase + (size_t)(s)*Dn + slot*8, (u16*)(smem + 32768 + (w*16 + 2*r)*512));
  }
  #pragma unroll
  for (int r=0;r<8;++r){
    int s = w*16 + 2*r + (lane>>5);
    int slot = (lane & 31) ^ (s & 7);
    gld_lds16(Kg + kbase + (size_t)(BS + s)*Dn + slot*8, (u16*)(smem + (w*16 + 2*r)*512));
  }
  asm volatile("s_waitcnt vmcnt(8)" ::: "memory");
  __builtin_amdgcn_sched_barrier(0);
  __builtin_amdgcn_s_barrier();

  float m_run = -INFINITY, l_run = 0.f;
  const int sr7 = l31 & 7;
  int cur = 1;
  for (int tile=0; tile<Tn/BS; ++tile){
    const char* kb = smem + cur*32768 + (sh*32 + l31)*512;
    f32x16 sc = (f32x16)(0.f);
    #pragma unroll
    for (int t=0;t<16;++t){
      bf16x8 kf = *(const bf16x8*)(kb + 16*((2*t+hi5)^sr7));
      sc = __builtin_amdgcn_mfma_f32_32x32x16_bf16(kf, qf[t], sc, 0,0,0);
    }
    float vmax = -INFINITY;
    float vals[16];
    #pragma unroll
    for (int i=0;i<16;++i){ float v = sc[i]*0.0625f; vals[i]=v; vmax=fmaxf(vmax,v); }
    vmax = fmaxf(vmax, __shfl_xor(vmax,32));
    float mnew = fmaxf(m_run, vmax);
    float corr = __expf(m_run - mnew);
    float esum = 0.f;
    #pragma unroll
    for (int i=0;i<16;++i) esum += __expf(vals[i]-mnew);
    esum += __shfl_xor(esum,32);
    l_run = l_run*corr + esum;
    m_run = mnew;

    asm volatile("s_waitcnt vmcnt(0)" ::: "memory");
    __builtin_amdgcn_sched_barrier(0);
    __builtin_amdgcn_s_barrier();
    if (tile < Tn/BS - 2){
      #pragma unroll
      for (int r=0;r<8;++r){
        int s = w*16 + 2*r + (lane>>5);
        int slot = (lane & 31) ^ (s & 7);
        gld_lds16(Kg + kbase + (size_t)((tile+2)*BS + s)*Dn + slot*8,
                  (u16*)(smem + cur*32768 + (w*16 + 2*r)*512));
      }
    }
    cur ^= 1;
  }
  __syncthreads();
  if (sh == 1 && lane < 32){
    float2 ml; ml.x = m_run; ml.y = l_run;
    *(float2*)(smem + (qh*32 + l31)*8) = ml;
  }
  __syncthreads();
  if (sh == 0){
    float2 o = *(const float2*)(smem + (qh*32 + l31)*8);
    float m2 = fmaxf(m_run, o.x);
    float lm = l_run*__expf(m_run - m2) + o.y*__expf(o.x - m2);
    if (lane < 32) mrow[row0 + qh*32 + l31] = m2;
    float r1 = 1.f/lm;
    #pragma unroll
    for (int off=1; off<64; off<<=1) r1 += __shfl_xor(r1, off);
    if (lane==0) atomicAdd(conf_b + b, r1*0.5f);
  }
}

// ---------------- pass B: single-buffer K/V (72KB, 2 blk/CU), reg prefetch, fixed max ----------------
#define KBF 0
#define VBF 32768
#define PST 65536
__global__ __launch_bounds__(512, 4) void k_passB(
    const u16* __restrict__ Qg, const u16* __restrict__ Kg, const u16* __restrict__ Vg,
    const float* __restrict__ conf_sum, const float* __restrict__ mrow,
    u16* __restrict__ Chi, u16* __restrict__ Clo)
{
  __shared__ __align__(16) char smem[73728];   // K 32K | V^T 32K | P 8K
  const int tid = threadIdx.x;
  const int lane = tid & 63, w = tid >> 6;
  const int qg = w & 3, hs = w >> 2;
  const int l7 = lane & 7, g = (lane >> 4) & 3, q15 = lane & 15;
  const int row0 = blockIdx.x * ABM;
  const int b = row0 >> 11;
  const size_t kbase = (size_t)b * Tn * Dn;
  float mean_rm = conf_sum[b] * (1.f/Tn);
  float uniform = 1.f/Tn;
  float conf = fminf(fmaxf((mean_rm - uniform)/(1.f - uniform + 1e-6f), 0.f), 1.f);
  const float scale = (2.f + 2.f*conf) * 0.0625f;
  const float mfix = mrow[row0 + qg*16 + q15] * scale * 16.f;  // exact sharp-max
  const int tid2 = tid & 255;
  const int dblk = tid2 >> 3, sblk = tid2 & 7;
  uint4 kreg[8], vreg[8];
  const int NT = Tn/BS;

  // prologue: Q -> KBF (waves 0-3) ; issue tile-0 reg loads
  if (hs == 0){
    #pragma unroll
    for (int r=0;r<8;++r){
      int s = w*16 + 2*r + (lane>>5);
      int slot = (lane & 31) ^ (s & 7);
      gld_lds16(Qg + (size_t)(row0 + s)*Dn + slot*8, (u16*)(smem + KBF + (w*16 + 2*r)*512));
    }
    #pragma unroll
    for (int r=0;r<8;++r){
      int s = w*16 + 2*r + (lane>>5);
      int slot = (lane & 31) ^ (s & 7);
      kreg[r] = *(const uint4*)(Kg + kbase + (size_t)s*Dn + slot*8);
    }
  } else {
    const u16* vsrc = Vg + kbase + (size_t)(sblk*8)*Dn + dblk*8;
    #pragma unroll
    for (int si=0; si<8; ++si) vreg[si] = *(const uint4*)(vsrc + (size_t)si*Dn);
  }
  __syncthreads();                         // Q staged (+t0 regs arrived)
  bf16x8 qf[8];
  {
    const char* qb = smem + KBF + (qg*16 + q15)*512;
    #pragma unroll
    for (int kk=0;kk<8;++kk) qf[kk] = *(const bf16x8*)(qb + 16*((4*kk+g)^l7));
  }
  __syncthreads();                         // all Q reads done
  // write tile 0 to LDS, prefetch tile 1 to regs
  if (hs == 0){
    #pragma unroll
    for (int r=0;r<8;++r)
      *(uint4*)(smem + KBF + (w*16 + 2*r)*512 + lane*16) = kreg[r];
    #pragma unroll
    for (int r=0;r<8;++r){
      int s = w*16 + 2*r + (lane>>5);
      int slot = (lane & 31) ^ (s & 7);
      kreg[r] = *(const uint4*)(Kg + kbase + (size_t)(BS + s)*Dn + slot*8);
    }
  } else {
    const u32* rw = (const u32*)vreg;
    #pragma unroll
    for (int dl=0; dl<8; ++dl){
      int wi = dl >> 1;
      u32 sel = (dl & 1) ? 0x07060302u : 0x05040100u;
      uint4 o;
      o.x = __builtin_amdgcn_perm(rw[1*4+wi], rw[0*4+wi], sel);
      o.y = __builtin_amdgcn_perm(rw[3*4+wi], rw[2*4+wi], sel);
      o.z = __builtin_amdgcn_perm(rw[5*4+wi], rw[4*4+wi], sel);
      o.w = __builtin_amdgcn_perm(rw[7*4+wi], rw[6*4+wi], sel);
      int d = dblk*8 + dl;
      *(uint4*)(smem + VBF + d*128 + 16*(sblk ^ dl)) = o;
    }
    const u16* vsrc = Vg + kbase + (size_t)(BS + sblk*8)*Dn + dblk*8;
    #pragma unroll
    for (int si=0; si<8; ++si) vreg[si] = *(const uint4*)(vsrc + (size_t)si*Dn);
  }
  asm volatile("s_waitcnt lgkmcnt(0)" ::: "memory");
  __builtin_amdgcn_sched_barrier(0);
  __builtin_amdgcn_s_barrier();            // K(0)/V^T(0) visible

  float l_run = 0.f;
  f32x4 oa[16];
  #pragma unroll
  for (int md=0;md<16;++md) oa[md] = (f32x4){0.f,0.f,0.f,0.f};

  char* pbase = smem + PST + w*1024 + q15*64;
  const int psw = q15 & 3;

  for (int tile=0; tile<NT; ++tile){
    // --- QK^T ---
    f32x4 sc[2];
    sc[0] = (f32x4){0.f,0.f,0.f,0.f};
    sc[1] = (f32x4){0.f,0.f,0.f,0.f};
    #pragma unroll
    for (int kk=0;kk<8;++kk){
      #pragma unroll
      for (int msl=0;msl<2;++msl){
        int msg = 2*hs + msl;
        bf16x8 kf = *(const bf16x8*)(smem + KBF + (msg*16+q15)*512 + 16*((4*kk+g)^l7));
        sc[msl] = __builtin_amdgcn_mfma_f32_16x16x32_bf16(kf, qf[kk], sc[msl], 0,0,0);
      }
    }
    // --- softmax with fixed max ---
    float vals[8];
    float esum = 0.f;
    #pragma unroll
    for (int msl=0;msl<2;++msl){
      #pragma unroll
      for (int j=0;j<4;++j){
        float p = __expf(sc[msl][j]*scale - mfix);
        vals[msl*4+j] = p; esum += p;
      }
    }
    esum += __shfl_xor(esum,16); esum += __shfl_xor(esum,32);
    l_run += esum;
    // --- P write ---
    #pragma unroll
    for (int msl=0;msl<2;++msl){
      uint2 pw;
      pw.x = (u32)f2bf(vals[msl*4+0]) | ((u32)f2bf(vals[msl*4+1]) << 16);
      pw.y = (u32)f2bf(vals[msl*4+2]) | ((u32)f2bf(vals[msl*4+3]) << 16);
      int slot = (2*msl + (g>>1)) ^ psw;
      *(uint2*)(pbase + slot*16 + (g&1)*8) = pw;
    }
    asm volatile("s_waitcnt lgkmcnt(0)" ::: "memory");
    __builtin_amdgcn_sched_barrier(0);
    // --- PV ---
    {
      bf16x8 pf = *(const bf16x8*)(pbase + ((g ^ psw)*16));
      #pragma unroll
      for (int md=0; md<16; ++md){
        bf16x8 vf = *(const bf16x8*)(smem + VBF + (md*16+q15)*128 + 16*((4*hs+g)^l7));
        oa[md] = __builtin_amdgcn_mfma_f32_16x16x32_bf16(vf, pf, oa[md], 0,0,0);
      }
    }
    asm volatile("s_waitcnt lgkmcnt(0)" ::: "memory");
    __builtin_amdgcn_sched_barrier(0);
    __builtin_amdgcn_s_barrier();          // all waves done reading K/V^T
    if (tile < NT-1){
      asm volatile("s_waitcnt vmcnt(0)" ::: "memory");   // t+1 regs arrived
      __builtin_amdgcn_sched_barrier(0);
      if (hs == 0){
        #pragma unroll
        for (int r=0;r<8;++r)
          *(uint4*)(smem + KBF + (w*16 + 2*r)*512 + lane*16) = kreg[r];
        if (tile < NT-2){
          #pragma unroll
          for (int r=0;r<8;++r){
            int s = w*16 + 2*r + (lane>>5);
            int slot = (lane & 31) ^ (s & 7);
            kreg[r] = *(const uint4*)(Kg + kbase + (size_t)((tile+2)*BS + s)*Dn + slot*8);
          }
        }
      } else {
        const u32* rw = (const u32*)vreg;
        #pragma unroll
        for (int dl=0; dl<8; ++dl){
          int wi = dl >> 1;
          u32 sel = (dl & 1) ? 0x07060302u : 0x05040100u;
          uint4 o;
          o.x = __builtin_amdgcn_perm(rw[1*4+wi], rw[0*4+wi], sel);
          o.y = __builtin_amdgcn_perm(rw[3*4+wi], rw[2*4+wi], sel);
          o.z = __builtin_amdgcn_perm(rw[5*4+wi], rw[4*4+wi], sel);
          o.w = __builtin_amdgcn_perm(rw[7*4+wi], rw[6*4+wi], sel);
          int d = dblk*8 + dl;
          *(uint4*)(smem + VBF + d*128 + 16*(sblk ^ dl)) = o;
        }
        if (tile < NT-2){
          const u16* vsrc = Vg + kbase + (size_t)((tile+2)*BS + sblk*8)*Dn + dblk*8;
          #pragma unroll
          for (int si=0; si<8; ++si) vreg[si] = *(const uint4*)(vsrc + (size_t)si*Dn);
        }
      }
      asm volatile("s_waitcnt lgkmcnt(0)" ::: "memory");
      __builtin_amdgcn_sched_barrier(0);
    }
    __builtin_amdgcn_s_barrier();          // next tile visible
  }
  // --- merge hs halves (fixed m -> plain sums) ---
  __syncthreads();
  if (hs == 1){
    char* ob_ = smem + (qg*64 + lane)*256;
    #pragma unroll
    for (int md=0; md<16; ++md)
      *(f32x4*)(ob_ + (md ^ q15)*16) = oa[md];
    *(float*)(smem + PST + (qg*64 + lane)*4) = l_run;
  }
  __syncthreads();
  if (hs == 0){
    float lo_ = *(const float*)(smem + PST + (qg*64 + lane)*4);
    float inv = 1.f / (l_run + lo_);
    const char* ob_ = smem + (qg*64 + lane)*256;
    const size_t rr = (size_t)(row0 + qg*16 + q15)*Dn + g*4;
    #pragma unroll
    for (int md=0; md<16; ++md){
      f32x4 ob = *(const f32x4*)(ob_ + (md ^ q15)*16);
      float v0 = (oa[md][0] + ob[0])*inv;
      float v1 = (oa[md][1] + ob[1])*inv;
      float v2 = (oa[md][2] + ob[2])*inv;
      float v3 = (oa[md][3] + ob[3])*inv;
      uint2 hi, lo;
      u16 h0=f2bf(v0), h1=f2bf(v1), h2=f2bf(v2), h3=f2bf(v3);
      hi.x = (u32)h0 | ((u32)h1 << 16);
      hi.y = (u32)h2 | ((u32)h3 << 16);
      lo.x = (u32)f2bf(v0 - bf2f(h0)) | ((u32)f2bf(v1 - bf2f(h1)) << 16);
      lo.y = (u32)f2bf(v2 - bf2f(h2)) | ((u32)f2bf(v3 - bf2f(h3)) << 16);
      *(uint2*)(Chi + rr + md*16) = hi;
      *(uint2*)(Clo + rr + md*16) = lo;
    }
  }
}

__global__ void k_finalize(const float* __restrict__ loss3, const float* __restrict__ conf_sum,
                           float* __restrict__ out_scalars){
  if (threadIdx.x == 0){
    float ls = (loss3[0]+loss3[1]+loss3[2]) * (1.f/(3.f*NROWS*Dn));
    float es = 0.f;
    float uniform = 1.f/Tn;
    #pragma unroll
    for (int i=0;i<NTICK*Bn;++i){
      float mean_rm = conf_sum[i] * (1.f/Tn);
      float conf = fminf(fmaxf((mean_rm - uniform)/(1.f - uniform + 1e-6f), 0.f), 1.f);
      es += 2.f + 2.f*conf;
    }
    out_scalars[0] = ls;
    out_scalars[1] = es * (1.f/(NTICK*Bn));
  }
}

extern "C" void kernel_launch(void* const* d_in, const int* in_sizes, int n_in,
                              void* d_out, int out_size, void* d_ws, size_t ws_size,
                              hipStream_t stream) {
  (void)in_sizes; (void)n_in; (void)out_size; (void)ws_size;
  const float* z_in   = (const float*)d_in[0];
  const float* in_w   = (const float*)d_in[1];
  const float* in_b   = (const float*)d_in[2];
  const float* ln_g   = (const float*)d_in[3];
  const float* ln_b   = (const float*)d_in[4];
  const float* q_w    = (const float*)d_in[5];
  const float* q_b    = (const float*)d_in[6];
  const float* k_w    = (const float*)d_in[7];
  const float* k_b    = (const float*)d_in[8];
  const float* v_w    = (const float*)d_in[9];
  const float* v_b    = (const float*)d_in[10];
  const float* o_w    = (const float*)d_in[11];
  const float* o_b    = (const float*)d_in[12];
  const float* log_tau= (const float*)d_in[13];
  const float* p1_w   = (const float*)d_in[14];
  const float* p1_b   = (const float*)d_in[15];
  const float* p2_w   = (const float*)d_in[16];
  const float* p2_b   = (const float*)d_in[17];

  float* out = (float*)d_out;
  const size_t NE = (size_t)NROWS * Dn;   // 4194304

  u16*  zh0  = (u16*)d_ws;
  u16*  zl0  = zh0 + NE;
  u16*  zh1  = zl0 + NE;
  u16*  zl1  = zh1 + NE;
  u16*  hbuf = zl1 + NE;
  u16*  Qb   = hbuf + NE;
  u16*  Kb   = Qb + NE;
  u16*  Vb   = Kb + NE;
  u16*  Chi  = Vb + NE;
  u16*  Clo  = Chi + NE;
  u16*  t1b  = Clo + NE;
  u16*  wbf  = t1b + NE;                // 14 x [256][256] bf16 (7 hi, 7 lo)
  float* stats = (float*)(wbf + 14*WP);
  float* conf_sum = stats;        // [3][8]
  float* loss     = stats + 24;   // [3]
  float* mrowb    = stats + 64;   // [16384] per-row sim-max (reused per tick)

  k_prep<<<dim3(64,7), 256, 0, stream>>>(in_w, q_w, k_w, v_w, o_w, p1_w, p2_w, wbf);
  k_split<<<4096, 256, 0, stream>>>(z_in, zh0, zl0, stats);

  u16* zh_list[2] = { zh0, zh1 };
  u16* zl_list[2] = { zl0, zl1 };

  for (int t = 0; t < NTICK; ++t){
    u16* zh_old = zh_list[t & 1];
    u16* zl_old = zl_list[t & 1];
    u16* zh_new = zh_list[(t+1) & 1];
    u16* zl_new = zl_list[(t+1) & 1];
    float* zout = (t == NTICK-1) ? out : nullptr;
    k_gemm_ln<<<NBLKG, 256, 0, stream>>>(zh_old, zl_old, wbf + 0*WP, wbf + 7*WP,
                                         in_b, ln_g, ln_b, hbuf);
    k_gemm_qkv<<<dim3(NBLKG,3), 256, 0, stream>>>(hbuf, wbf, q_b, k_b, v_b, Qb, Kb, Vb);
    k_passA<<<NBLKA, 256, 0, stream>>>(Qb, Kb, conf_sum + t*8, mrowb);
    k_passB<<<NBLKA, 512, 0, stream>>>(Qb, Kb, Vb, conf_sum + t*8, mrowb, Chi, Clo);
    k_gemm_update<<<NBLKG, 256, 0, stream>>>(Chi, Clo, wbf + 4*WP, wbf + 11*WP, o_b,
                                             zh_old, zl_old, log_tau, zh_new, zl_new, zout);
    k_gemm_relu<<<NBLKG, 256, 0, stream>>>(zh_old, wbf + 5*WP, p1_b, t1b);
    k_gemm_loss<<<NBLKG, 256, 0, stream>>>(t1b, wbf + 6*WP, p2_b, zh_new, zl_new, loss + t);
  }
  k_finalize<<<1, 64, 0, stream>>>(loss, conf_sum, out + NE);
}

// Round 14
// 735.145 us; speedup vs baseline: 2.2813x; 2.2813x over previous
//
#include <hip/hip_runtime.h>
#include <math.h>

#define Bn 8
#define Tn 2048
#define Dn 256
#define NTICK 3
#define NROWS (Bn*Tn)      // 16384
#define ABM 64             // attention Q-rows per block
#define NBLKA (NROWS/ABM)  // 256
#define BS 64              // KV tile
#define GM 64              // GEMM rows per block
#define NBLKG (NROWS/GM)   // 256
#define WP 65536           // weight plane elems (256*256)

typedef unsigned int u32;
typedef unsigned short u16;
typedef __attribute__((ext_vector_type(8))) short bf16x8;
typedef __attribute__((ext_vector_type(4))) float f32x4;
typedef __attribute__((ext_vector_type(16))) float f32x16;

__device__ __forceinline__ float bf2f(u32 u){
  union { u32 i; float f; } x; x.i = u << 16; return x.f;
}
__device__ __forceinline__ u16 f2bf(float f){
  union { float f; u32 i; } x; x.f = f;
  u32 r = (x.i + 0x7fffu + ((x.i >> 16) & 1u)) >> 16;
  return (u16)r;
}
// async global->LDS 16B: per-lane global src, wave-uniform LDS base + lane*16
__device__ __forceinline__ void gld_lds16(const u16* gsrc, u16* ldst){
  __builtin_amdgcn_global_load_lds(
      (const __attribute__((address_space(1))) u32*)(const void*)gsrc,
      (__attribute__((address_space(3))) u32*)(void*)ldst, 16, 0, 0);
}

// ======== GEMM building blocks ========
__device__ __forceinline__ void stage_A(const u16* __restrict__ A, int row0, char* smem){
  const int tid = threadIdx.x, lane = tid & 63, w = tid >> 6;
  #pragma unroll
  for (int r=0;r<8;++r){
    int s = w*16 + 2*r + (lane>>5);
    int slot = (lane & 31) ^ (s & 7);
    gld_lds16(A + (size_t)(row0 + s)*Dn + slot*8, (u16*)(smem + (w*16 + 2*r)*512));
  }
}
__device__ __forceinline__ void load_frags(const char* smem, bf16x8* af){
  const int tid = threadIdx.x, lane = tid & 63, w = tid >> 6;
  const int l7 = lane & 7, g = (lane >> 4) & 3, q15 = lane & 15;
  const char* ab = smem + (w*16 + q15)*512;
  #pragma unroll
  for (int kk=0;kk<8;++kk) af[kk] = *(const bf16x8*)(ab + 16*((4*kk+g)^l7));
}
// stage one 16-row W chunk (8KB) block-cooperatively (2 gld/thread), stage_A swizzle
__device__ __forceinline__ void stage_Wchunk(const u16* __restrict__ W, int c, char* wbuf){
  const int tid = threadIdx.x, lane = tid & 63, w = tid >> 6;
  #pragma unroll
  for (int r=0;r<2;++r){
    int rl = w*4 + 2*r + (lane>>5);
    int slot = (lane & 31) ^ (rl & 7);
    gld_lds16(W + (size_t)(c*16 + rl)*Dn + slot*8, (u16*)(wbuf + (w*4 + 2*r)*512));
  }
}
__device__ __forceinline__ void load_wfrags(const char* wbuf, bf16x8* wf){
  const int lane = threadIdx.x & 63;
  const int l7 = lane & 7, g = (lane >> 4) & 3, q15 = lane & 15;
  const char* wb_ = wbuf + q15*512;
  #pragma unroll
  for (int kk=0;kk<8;++kk) wf[kk] = *(const bf16x8*)(wb_ + 16*((4*kk+g)^l7));
}
__device__ __forceinline__ void zero_acc(f32x4* acc){
  #pragma unroll
  for (int nt=0;nt<16;++nt) acc[nt] = (f32x4){0.f,0.f,0.f,0.f};
}
#define CHUNK_STEP(c, NC, PLANE_OF, IDX_OF)                                    \
  asm volatile("s_waitcnt lgkmcnt(0)" ::: "memory");                           \
  if ((c) < (NC)-2) { asm volatile("s_waitcnt vmcnt(2)" ::: "memory"); }       \
  else              { asm volatile("s_waitcnt vmcnt(0)" ::: "memory"); }       \
  __builtin_amdgcn_sched_barrier(0);                                           \
  __builtin_amdgcn_s_barrier();                                                \
  if ((c)+3 < (NC)) stage_Wchunk(PLANE_OF((c)+3), IDX_OF((c)+3), ring + (((c)+3)&3)*8192);

// ---------------- weights f32 -> (hi, lo) bf16 planes ----------------
__global__ void k_prep(const float* __restrict__ s0, const float* __restrict__ s1,
                       const float* __restrict__ s2, const float* __restrict__ s3,
                       const float* __restrict__ s4, const float* __restrict__ s5,
                       const float* __restrict__ s6, u16* __restrict__ dst){
  int y = blockIdx.y;
  const float* s = (y==0)?s0:(y==1)?s1:(y==2)?s2:(y==3)?s3:(y==4)?s4:(y==5)?s5:s6;
  int i = (blockIdx.x*256 + threadIdx.x)*4;
  float4 v = *(const float4*)(s + i);
  u16 h0=f2bf(v.x), h1=f2bf(v.y), h2=f2bf(v.z), h3=f2bf(v.w);
  uint2 hi, lo;
  hi.x = (u32)h0 | ((u32)h1 << 16);
  hi.y = (u32)h2 | ((u32)h3 << 16);
  lo.x = (u32)f2bf(v.x - bf2f(h0)) | ((u32)f2bf(v.y - bf2f(h1)) << 16);
  lo.y = (u32)f2bf(v.z - bf2f(h2)) | ((u32)f2bf(v.w - bf2f(h3)) << 16);
  *(uint2*)(dst + (size_t)y*WP + i) = hi;
  *(uint2*)(dst + (size_t)(7+y)*WP + i) = lo;
}

// ---------------- z f32 -> (hi, lo) ; also zero stats ----------------
__global__ void k_split(const float* __restrict__ s, u16* __restrict__ dh, u16* __restrict__ dl,
                        float* __restrict__ stats){
  if (blockIdx.x == 0 && threadIdx.x < 64) stats[threadIdx.x] = 0.f;
  int i = (blockIdx.x*256 + threadIdx.x)*4;
  float4 v = *(const float4*)(s + i);
  u16 h0=f2bf(v.x), h1=f2bf(v.y), h2=f2bf(v.z), h3=f2bf(v.w);
  uint2 hi, lo;
  hi.x = (u32)h0 | ((u32)h1 << 16);
  hi.y = (u32)h2 | ((u32)h3 << 16);
  lo.x = (u32)f2bf(v.x - bf2f(h0)) | ((u32)f2bf(v.y - bf2f(h1)) << 16);
  lo.y = (u32)f2bf(v.z - bf2f(h2)) | ((u32)f2bf(v.w - bf2f(h3)) << 16);
  *(uint2*)(dh + i) = hi;
  *(uint2*)(dl + i) = lo;
}

// ---------------- h = LN(z @ in_w^T + in_b) * g + beta -> bf16 (split z, split W) ----------------
__global__ __launch_bounds__(256) void k_gemm_ln(
    const u16* __restrict__ Ahi, const u16* __restrict__ Alo,
    const u16* __restrict__ Whi, const u16* __restrict__ Wlo,
    const float* __restrict__ bias, const float* __restrict__ gamma, const float* __restrict__ beta,
    u16* __restrict__ h)
{
  __shared__ __align__(16) char smem[65536];
  char* ring = smem;
  f32x4 acc[16];
  const int row0 = blockIdx.x * GM;
  stage_A(Ahi, row0, smem);
  stage_A(Alo, row0, smem + 32768);
  asm volatile("s_waitcnt vmcnt(0)" ::: "memory");
  __builtin_amdgcn_sched_barrier(0);
  bf16x8 afh[8], afl[8];
  load_frags(smem, afh);
  load_frags(smem + 32768, afl);
  asm volatile("s_waitcnt lgkmcnt(0)" ::: "memory");
  __builtin_amdgcn_sched_barrier(0);
  __builtin_amdgcn_s_barrier();
  zero_acc(acc);
  #define LN_PL(i) ((i) < 16 ? Whi : Wlo)
  #define LN_IX(i) ((i) & 15)
  stage_Wchunk(LN_PL(0), LN_IX(0), ring + 0*8192);
  stage_Wchunk(LN_PL(1), LN_IX(1), ring + 1*8192);
  stage_Wchunk(LN_PL(2), LN_IX(2), ring + 2*8192);
  asm volatile("s_waitcnt vmcnt(4)" ::: "memory");
  __builtin_amdgcn_sched_barrier(0);
  __builtin_amdgcn_s_barrier();
  for (int c=0; c<32; ++c){
    bf16x8 wf[8];
    load_wfrags(ring + (c&3)*8192, wf);
    int nt = c & 15;
    if (c < 16){
      #pragma unroll
      for (int kk=0;kk<8;++kk)
        acc[nt] = __builtin_amdgcn_mfma_f32_16x16x32_bf16(afh[kk], wf[kk], acc[nt], 0,0,0);
      #pragma unroll
      for (int kk=0;kk<8;++kk)
        acc[nt] = __builtin_amdgcn_mfma_f32_16x16x32_bf16(afl[kk], wf[kk], acc[nt], 0,0,0);
    } else {
      #pragma unroll
      for (int kk=0;kk<8;++kk)
        acc[nt] = __builtin_amdgcn_mfma_f32_16x16x32_bf16(afh[kk], wf[kk], acc[nt], 0,0,0);
    }
    CHUNK_STEP(c, 32, LN_PL, LN_IX)
  }
  const int tid = threadIdx.x, lane = tid & 63, w = tid >> 6;
  const int g4 = lane >> 4, q15 = lane & 15;
  float bcol[16], gcol[16], becol[16];
  #pragma unroll
  for (int nt=0;nt<16;++nt){
    int col = nt*16 + q15;
    bcol[nt] = bias[col]; gcol[nt] = gamma[col]; becol[nt] = beta[col];
  }
  float mu[4], rstd[4];
  #pragma unroll
  for (int j=0;j<4;++j){
    float s=0.f, q=0.f;
    #pragma unroll
    for (int nt=0;nt<16;++nt){ float v = acc[nt][j] + bcol[nt]; s += v; q += v*v; }
    #pragma unroll
    for (int off=1; off<16; off<<=1){ s += __shfl_xor(s,off); q += __shfl_xor(q,off); }
    float m = s*(1.f/Dn);
    mu[j] = m; rstd[j] = rsqrtf(q*(1.f/Dn) - m*m + 1e-5f);
  }
  const size_t rbase = (size_t)(row0 + w*16 + g4*4);
  #pragma unroll
  for (int nt=0;nt<16;++nt){
    #pragma unroll
    for (int j=0;j<4;++j){
      float v = (acc[nt][j] + bcol[nt] - mu[j])*rstd[j]*gcol[nt] + becol[nt];
      h[(rbase+j)*Dn + nt*16 + q15] = f2bf(v);
    }
  }
}

// ---------------- Q/K/V = h @ w^T + b -> bf16 (split W, 3-dispatch) ----------------
__global__ __launch_bounds__(256) void k_gemm_qkv(
    const u16* __restrict__ h, const u16* __restrict__ wbf,
    const float* __restrict__ qb, const float* __restrict__ kb, const float* __restrict__ vb,
    u16* __restrict__ Qo, u16* __restrict__ Ko, u16* __restrict__ Vo)
{
  const u16 *Whi, *Wlo; const float* bias; u16* out;
  if (blockIdx.y == 0){ Whi = wbf + 1*WP; Wlo = wbf + 8*WP;  bias = qb; out = Qo; }
  else if (blockIdx.y == 1){ Whi = wbf + 2*WP; Wlo = wbf + 9*WP;  bias = kb; out = Ko; }
  else { Whi = wbf + 3*WP; Wlo = wbf + 10*WP; bias = vb; out = Vo; }
  __shared__ __align__(16) char smem[65536];
  char* ring = smem + 32768;
  f32x4 acc[16];
  const int row0 = blockIdx.x * GM;
  stage_A(h, row0, smem);
  #define QK_PL(i) ((i) < 16 ? Whi : Wlo)
  #define QK_IX(i) ((i) & 15)
  stage_Wchunk(QK_PL(0), QK_IX(0), ring + 0*8192);
  stage_Wchunk(QK_PL(1), QK_IX(1), ring + 1*8192);
  stage_Wchunk(QK_PL(2), QK_IX(2), ring + 2*8192);
  asm volatile("s_waitcnt vmcnt(4)" ::: "memory");   // A + chunk0 (mine) done
  __builtin_amdgcn_sched_barrier(0);
  bf16x8 af[8];
  load_frags(smem, af);
  zero_acc(acc);
  __builtin_amdgcn_s_barrier();                      // chunk0 staged (all)
  for (int c=0; c<32; ++c){
    bf16x8 wf[8];
    load_wfrags(ring + (c&3)*8192, wf);
    int nt = c & 15;
    #pragma unroll
    for (int kk=0;kk<8;++kk)
      acc[nt] = __builtin_amdgcn_mfma_f32_16x16x32_bf16(af[kk], wf[kk], acc[nt], 0,0,0);
    CHUNK_STEP(c, 32, QK_PL, QK_IX)
  }
  const int tid = threadIdx.x, lane = tid & 63, w = tid >> 6;
  const int g4 = lane >> 4, q15 = lane & 15;
  const size_t rbase = (size_t)(row0 + w*16 + g4*4);
  #pragma unroll
  for (int nt=0;nt<16;++nt){
    float bc = bias[nt*16 + q15];
    #pragma unroll
    for (int j=0;j<4;++j)
      out[(rbase+j)*Dn + nt*16 + q15] = f2bf(acc[nt][j] + bc);
  }
}

// ---------------- update: z_new = z + ((ctx @ o_w^T + o_b) - z)/(tau+1e-6) ----------------
__global__ __launch_bounds__(256) void k_gemm_update(
    const u16* __restrict__ Chi, const u16* __restrict__ Clo,
    const u16* __restrict__ Whi, const u16* __restrict__ Wlo,
    const float* __restrict__ ob,
    const u16* __restrict__ zhi_old, const u16* __restrict__ zlo_old,
    const float* __restrict__ log_tau,
    u16* __restrict__ zhi_new, u16* __restrict__ zlo_new,
    float* __restrict__ zout)
{
  __shared__ __align__(16) char smem[65536];
  char* ring = smem;
  f32x4 acc[16];
  const int row0 = blockIdx.x * GM;
  stage_A(Chi, row0, smem);
  stage_A(Clo, row0, smem + 32768);
  asm volatile("s_waitcnt vmcnt(0)" ::: "memory");
  __builtin_amdgcn_sched_barrier(0);
  bf16x8 afh[8], afl[8];
  load_frags(smem, afh);
  load_frags(smem + 32768, afl);
  asm volatile("s_waitcnt lgkmcnt(0)" ::: "memory");
  __builtin_amdgcn_sched_barrier(0);
  __builtin_amdgcn_s_barrier();
  zero_acc(acc);
  stage_Wchunk(LN_PL(0), LN_IX(0), ring + 0*8192);
  stage_Wchunk(LN_PL(1), LN_IX(1), ring + 1*8192);
  stage_Wchunk(LN_PL(2), LN_IX(2), ring + 2*8192);
  asm volatile("s_waitcnt vmcnt(4)" ::: "memory");
  __builtin_amdgcn_sched_barrier(0);
  __builtin_amdgcn_s_barrier();
  for (int c=0; c<32; ++c){
    bf16x8 wf[8];
    load_wfrags(ring + (c&3)*8192, wf);
    int nt = c & 15;
    if (c < 16){
      #pragma unroll
      for (int kk=0;kk<8;++kk)
        acc[nt] = __builtin_amdgcn_mfma_f32_16x16x32_bf16(afh[kk], wf[kk], acc[nt], 0,0,0);
      #pragma unroll
      for (int kk=0;kk<8;++kk)
        acc[nt] = __builtin_amdgcn_mfma_f32_16x16x32_bf16(afl[kk], wf[kk], acc[nt], 0,0,0);
    } else {
      #pragma unroll
      for (int kk=0;kk<8;++kk)
        acc[nt] = __builtin_amdgcn_mfma_f32_16x16x32_bf16(afh[kk], wf[kk], acc[nt], 0,0,0);
    }
    CHUNK_STEP(c, 32, LN_PL, LN_IX)
  }
  const int tid = threadIdx.x, lane = tid & 63, w = tid >> 6;
  const int g4 = lane >> 4, q15 = lane & 15;
  const size_t rbase = (size_t)(row0 + w*16 + g4*4);
  #pragma unroll
  for (int nt=0;nt<16;++nt){
    int col = nt*16 + q15;
    float bc = ob[col];
    float invt = 1.f/(expf(log_tau[col]) + 1e-6f);
    #pragma unroll
    for (int j=0;j<4;++j){
      size_t idx = (rbase+j)*Dn + col;
      float zo = bf2f(zhi_old[idx]) + bf2f(zlo_old[idx]);
      float zn = zo + (acc[nt][j] + bc - zo)*invt;
      u16 zh = f2bf(zn);
      zhi_new[idx] = zh;
      zlo_new[idx] = f2bf(zn - bf2f(zh));
      if (zout) zout[idx] = zn;
    }
  }
}

// ---------------- t1 = relu(zhi @ p1^T + b1) -> bf16 ----------------
__global__ __launch_bounds__(256) void k_gemm_relu(
    const u16* __restrict__ A, const u16* __restrict__ Wb, const float* __restrict__ bias,
    u16* __restrict__ t1)
{
  __shared__ __align__(16) char smem[65536];
  char* ring = smem + 32768;
  f32x4 acc[16];
  const int row0 = blockIdx.x * GM;
  stage_A(A, row0, smem);
  #define W1_PL(i) (Wb)
  #define W1_IX(i) (i)
  stage_Wchunk(Wb, 0, ring + 0*8192);
  stage_Wchunk(Wb, 1, ring + 1*8192);
  stage_Wchunk(Wb, 2, ring + 2*8192);
  asm volatile("s_waitcnt vmcnt(4)" ::: "memory");
  __builtin_amdgcn_sched_barrier(0);
  bf16x8 af[8];
  load_frags(smem, af);
  zero_acc(acc);
  __builtin_amdgcn_s_barrier();
  for (int c=0; c<16; ++c){
    bf16x8 wf[8];
    load_wfrags(ring + (c&3)*8192, wf);
    #pragma unroll
    for (int kk=0;kk<8;++kk)
      acc[c] = __builtin_amdgcn_mfma_f32_16x16x32_bf16(af[kk], wf[kk], acc[c], 0,0,0);
    CHUNK_STEP(c, 16, W1_PL, W1_IX)
  }
  const int tid = threadIdx.x, lane = tid & 63, w = tid >> 6;
  const int g4 = lane >> 4, q15 = lane & 15;
  const size_t rbase = (size_t)(row0 + w*16 + g4*4);
  #pragma unroll
  for (int nt=0;nt<16;++nt){
    float bc = bias[nt*16 + q15];
    #pragma unroll
    for (int j=0;j<4;++j)
      t1[(rbase+j)*Dn + nt*16 + q15] = f2bf(fmaxf(acc[nt][j] + bc, 0.f));
  }
}

// ---------------- loss += sum((t1 @ p2^T + b2 - z_new)^2) ----------------
__global__ __launch_bounds__(256) void k_gemm_loss(
    const u16* __restrict__ t1, const u16* __restrict__ Wb, const float* __restrict__ bias,
    const u16* __restrict__ zhi_new, const u16* __restrict__ zlo_new,
    float* __restrict__ loss_acc)
{
  __shared__ __align__(16) char smem[65536];
  __shared__ float red[4];
  char* ring = smem + 32768;
  f32x4 acc[16];
  const int row0 = blockIdx.x * GM;
  stage_A(t1, row0, smem);
  stage_Wchunk(Wb, 0, ring + 0*8192);
  stage_Wchunk(Wb, 1, ring + 1*8192);
  stage_Wchunk(Wb, 2, ring + 2*8192);
  asm volatile("s_waitcnt vmcnt(4)" ::: "memory");
  __builtin_amdgcn_sched_barrier(0);
  bf16x8 af[8];
  load_frags(smem, af);
  zero_acc(acc);
  __builtin_amdgcn_s_barrier();
  for (int c=0; c<16; ++c){
    bf16x8 wf[8];
    load_wfrags(ring + (c&3)*8192, wf);
    #pragma unroll
    for (int kk=0;kk<8;++kk)
      acc[c] = __builtin_amdgcn_mfma_f32_16x16x32_bf16(af[kk], wf[kk], acc[c], 0,0,0);
    CHUNK_STEP(c, 16, W1_PL, W1_IX)
  }
  const int tid = threadIdx.x, lane = tid & 63, w = tid >> 6;
  const int g4 = lane >> 4, q15 = lane & 15;
  const size_t rbase = (size_t)(row0 + w*16 + g4*4);
  float lsum = 0.f;
  #pragma unroll
  for (int nt=0;nt<16;++nt){
    float bc = bias[nt*16 + q15];
    #pragma unroll
    for (int j=0;j<4;++j){
      size_t idx = (rbase+j)*Dn + nt*16 + q15;
      float zn = bf2f(zhi_new[idx]) + bf2f(zlo_new[idx]);
      float dn = acc[nt][j] + bc - zn;
      lsum += dn*dn;
    }
  }
  #pragma unroll
  for (int off=1; off<64; off<<=1) lsum += __shfl_xor(lsum, off);
  if (lane == 0) red[w] = lsum;
  __syncthreads();
  if (tid == 0) atomicAdd(loss_acc, red[0]+red[1]+red[2]+red[3]);
}

// ---------------- pass A: 32x32 MFMA, K dbuf; also stores per-row max ----------------
__global__ __launch_bounds__(256) void k_passA(
    const u16* __restrict__ Qg, const u16* __restrict__ Kg,
    float* __restrict__ conf_b, float* __restrict__ mrow)
{
  __shared__ __align__(16) char smem[65536];
  const int tid = threadIdx.x;
  const int lane = tid & 63, w = tid >> 6;
  const int l31 = lane & 31, hi5 = lane >> 5;
  const int qh = w >> 1, sh = w & 1;
  const int row0 = blockIdx.x * ABM;
  const int b = row0 >> 11;
  const size_t kbase = (size_t)b * Tn * Dn;

  #pragma unroll
  for (int r=0;r<8;++r){
    int s = w*16 + 2*r + (lane>>5);
    int slot = (lane & 31) ^ (s & 7);
    gld_lds16(Qg + (size_t)(row0 + s)*Dn + slot*8, (u16*)(smem + (w*16 + 2*r)*512));
  }
  asm volatile("s_waitcnt vmcnt(0)" ::: "memory");
  __builtin_amdgcn_sched_barrier(0);
  __builtin_amdgcn_s_barrier();                      // Q visible to all
  bf16x8 qf[16];
  {
    const char* qb = smem + (qh*32 + l31)*512;
    const int r7 = l31 & 7;
    #pragma unroll
    for (int t=0;t<16;++t) qf[t] = *(const bf16x8*)(qb + 16*((2*t+hi5)^r7));
  }
  asm volatile("s_waitcnt lgkmcnt(0)" ::: "memory");
  __builtin_amdgcn_sched_barrier(0);
  __builtin_amdgcn_s_barrier();                      // all Q reads done
  #pragma unroll
  for (int r=0;r<8;++r){
    int s = w*16 + 2*r + (lane>>5);
    int slot = (lane & 31) ^ (s & 7);
    gld_lds16(Kg + kbase + (size_t)(s)*Dn + slot*8, (u16*)(smem + 32768 + (w*16 + 2*r)*512));
  }
  #pragma unroll
  for (int r=0;r<8;++r){
    int s = w*16 + 2*r + (lane>>5);
    int slot = (lane & 31) ^ (s & 7);
    gld_lds16(Kg + kbase + (size_t)(BS + s)*Dn + slot*8, (u16*)(smem + (w*16 + 2*r)*512));
  }
  asm volatile("s_waitcnt vmcnt(8)" ::: "memory");
  __builtin_amdgcn_sched_barrier(0);
  __builtin_amdgcn_s_barrier();

  float m_run = -INFINITY, l_run = 0.f;
  const int sr7 = l31 & 7;
  int cur = 1;
  for (int tile=0; tile<Tn/BS; ++tile){
    const char* kb = smem + cur*32768 + (sh*32 + l31)*512;
    f32x16 sc = (f32x16)(0.f);
    #pragma unroll
    for (int t=0;t<16;++t){
      bf16x8 kf = *(const bf16x8*)(kb + 16*((2*t+hi5)^sr7));
      sc = __builtin_amdgcn_mfma_f32_32x32x16_bf16(kf, qf[t], sc, 0,0,0);
    }
    float vmax = -INFINITY;
    float vals[16];
    #pragma unroll
    for (int i=0;i<16;++i){ float v = sc[i]*0.0625f; vals[i]=v; vmax=fmaxf(vmax,v); }
    vmax = fmaxf(vmax, __shfl_xor(vmax,32));
    float mnew = fmaxf(m_run, vmax);
    float corr = __expf(m_run - mnew);
    float esum = 0.f;
    #pragma unroll
    for (int i=0;i<16;++i) esum += __expf(vals[i]-mnew);
    esum += __shfl_xor(esum,32);
    l_run = l_run*corr + esum;
    m_run = mnew;

    asm volatile("s_waitcnt vmcnt(0)" ::: "memory");
    __builtin_amdgcn_sched_barrier(0);
    __builtin_amdgcn_s_barrier();
    if (tile < Tn/BS - 2){
      #pragma unroll
      for (int r=0;r<8;++r){
        int s = w*16 + 2*r + (lane>>5);
        int slot = (lane & 31) ^ (s & 7);
        gld_lds16(Kg + kbase + (size_t)((tile+2)*BS + s)*Dn + slot*8,
                  (u16*)(smem + cur*32768 + (w*16 + 2*r)*512));
      }
    }
    cur ^= 1;
  }
  __syncthreads();
  if (sh == 1 && lane < 32){
    float2 ml; ml.x = m_run; ml.y = l_run;
    *(float2*)(smem + (qh*32 + l31)*8) = ml;
  }
  __syncthreads();
  if (sh == 0){
    float2 o = *(const float2*)(smem + (qh*32 + l31)*8);
    float m2 = fmaxf(m_run, o.x);
    float lm = l_run*__expf(m_run - m2) + o.y*__expf(o.x - m2);
    if (lane < 32) mrow[row0 + qh*32 + l31] = m2;
    float r1 = 1.f/lm;
    #pragma unroll
    for (int off=1; off<64; off<<=1) r1 += __shfl_xor(r1, off);
    if (lane==0) atomicAdd(conf_b + b, r1*0.5f);
  }
}

// ---------------- pass B: R12 structure (K dbuf gld_lds + V vreg dbuf), fixed max ----------------
#define KB0 0
#define KB1 32768
#define VT0 65536
#define VT1 98304
#define PST 131072
__global__ __launch_bounds__(512) void k_passB(
    const u16* __restrict__ Qg, const u16* __restrict__ Kg, const u16* __restrict__ Vg,
    const float* __restrict__ conf_sum, const float* __restrict__ mrow,
    u16* __restrict__ Chi, u16* __restrict__ Clo)
{
  __shared__ __align__(16) char smem[139264];
  const int tid = threadIdx.x;
  const int lane = tid & 63, w = tid >> 6;
  const int qg = w & 3, hs = w >> 2;
  const int l7 = lane & 7, g = (lane >> 4) & 3, q15 = lane & 15;
  const int row0 = blockIdx.x * ABM;
  const int b = row0 >> 11;
  const size_t kbase = (size_t)b * Tn * Dn;
  float mean_rm = conf_sum[b] * (1.f/Tn);
  float uniform = 1.f/Tn;
  float conf = fminf(fmaxf((mean_rm - uniform)/(1.f - uniform + 1e-6f), 0.f), 1.f);
  const float scale = (2.f + 2.f*conf) * 0.0625f;
  const float mfix = mrow[row0 + qg*16 + q15] * scale * 16.f;  // exact sharp-max
  const int tid2 = tid & 255;
  const int dblk = tid2 >> 3, sblk = tid2 & 7;
  uint4 vreg[8];
  const int NT = Tn/BS;

  if (hs == 0){
    #pragma unroll
    for (int r=0;r<8;++r){
      int s = w*16 + 2*r + (lane>>5);
      int slot = (lane & 31) ^ (s & 7);
      gld_lds16(Qg + (size_t)(row0 + s)*Dn + slot*8, (u16*)(smem + KB0 + (w*16 + 2*r)*512));
    }
  } else {
    const u16* vsrc = Vg + kbase + (size_t)(sblk*8)*Dn + dblk*8;
    #pragma unroll
    for (int si=0; si<8; ++si) vreg[si] = *(const uint4*)(vsrc + (size_t)si*Dn);
  }
  __syncthreads();
  bf16x8 qf[8];
  {
    const char* qb = smem + KB0 + (qg*16 + q15)*512;
    #pragma unroll
    for (int kk=0;kk<8;++kk) qf[kk] = *(const bf16x8*)(qb + 16*((4*kk+g)^l7));
  }
  __syncthreads();
  if (hs == 0){
    #pragma unroll
    for (int r=0;r<8;++r){
      int s = w*16 + 2*r + (lane>>5);
      int slot = (lane & 31) ^ (s & 7);
      gld_lds16(Kg + kbase + (size_t)(s)*Dn + slot*8, (u16*)(smem + KB0 + (w*16 + 2*r)*512));
    }
    #pragma unroll
    for (int r=0;r<8;++r){
      int s = w*16 + 2*r + (lane>>5);
      int slot = (lane & 31) ^ (s & 7);
      gld_lds16(Kg + kbase + (size_t)(BS + s)*Dn + slot*8, (u16*)(smem + KB1 + (w*16 + 2*r)*512));
    }
    asm volatile("s_waitcnt vmcnt(8)" ::: "memory");
    __builtin_amdgcn_sched_barrier(0);
  } else {
    const u32* rw = (const u32*)vreg;
    #pragma unroll
    for (int dl=0; dl<8; ++dl){
      int wi = dl >> 1;
      u32 sel = (dl & 1) ? 0x07060302u : 0x05040100u;
      uint4 o;
      o.x = __builtin_amdgcn_perm(rw[1*4+wi], rw[0*4+wi], sel);
      o.y = __builtin_amdgcn_perm(rw[3*4+wi], rw[2*4+wi], sel);
      o.z = __builtin_amdgcn_perm(rw[5*4+wi], rw[4*4+wi], sel);
      o.w = __builtin_amdgcn_perm(rw[7*4+wi], rw[6*4+wi], sel);
      int d = dblk*8 + dl;
      *(uint4*)(smem + VT0 + d*128 + 16*(sblk ^ dl)) = o;
    }
    asm volatile("s_waitcnt lgkmcnt(0)" ::: "memory");
    __builtin_amdgcn_sched_barrier(0);
  }
  __builtin_amdgcn_s_barrier();

  float l_run = 0.f;
  f32x4 oa[16];
  #pragma unroll
  for (int md=0;md<16;++md) oa[md] = (f32x4){0.f,0.f,0.f,0.f};

  char* pbase = smem + PST + w*1024 + q15*64;
  const int psw = q15 & 3;

  int cur = 0;
  for (int tile=0; tile<NT; ++tile){
    const char* kbuf = smem + (cur ? KB1 : KB0);
    const char* vbuf = smem + (cur ? VT1 : VT0);
    char* vbuf_n = (char*)smem + (cur ? VT0 : VT1);
    if (hs == 1 && tile < NT-1){
      const u16* vsrc = Vg + kbase + (size_t)((tile+1)*BS + sblk*8)*Dn + dblk*8;
      #pragma unroll
      for (int si=0; si<8; ++si) vreg[si] = *(const uint4*)(vsrc + (size_t)si*Dn);
    }
    f32x4 sc[2];
    sc[0] = (f32x4){0.f,0.f,0.f,0.f};
    sc[1] = (f32x4){0.f,0.f,0.f,0.f};
    #pragma unroll
    for (int kk=0;kk<8;++kk){
      #pragma unroll
      for (int msl=0;msl<2;++msl){
        int msg = 2*hs + msl;
        bf16x8 kf = *(const bf16x8*)(kbuf + (msg*16+q15)*512 + 16*((4*kk+g)^l7));
        sc[msl] = __builtin_amdgcn_mfma_f32_16x16x32_bf16(kf, qf[kk], sc[msl], 0,0,0);
      }
    }
    // --- softmax with fixed max (no rescale, no max reduce) ---
    float vals[8];
    float esum = 0.f;
    #pragma unroll
    for (int msl=0;msl<2;++msl){
      #pragma unroll
      for (int j=0;j<4;++j){
        float p = __expf(sc[msl][j]*scale - mfix);
        vals[msl*4+j] = p; esum += p;
      }
    }
    esum += __shfl_xor(esum,16); esum += __shfl_xor(esum,32);
    l_run += esum;
    #pragma unroll
    for (int msl=0;msl<2;++msl){
      uint2 pw;
      pw.x = (u32)f2bf(vals[msl*4+0]) | ((u32)f2bf(vals[msl*4+1]) << 16);
      pw.y = (u32)f2bf(vals[msl*4+2]) | ((u32)f2bf(vals[msl*4+3]) << 16);
      int slot = (2*msl + (g>>1)) ^ psw;
      *(uint2*)(pbase + slot*16 + (g&1)*8) = pw;
    }
    asm volatile("s_waitcnt lgkmcnt(0)" ::: "memory");
    __builtin_amdgcn_sched_barrier(0);
    {
      bf16x8 pf = *(const bf16x8*)(pbase + ((g ^ psw)*16));
      #pragma unroll
      for (int md=0; md<16; ++md){
        bf16x8 vf = *(const bf16x8*)(vbuf + (md*16+q15)*128 + 16*((4*hs+g)^l7));
        oa[md] = __builtin_amdgcn_mfma_f32_16x16x32_bf16(vf, pf, oa[md], 0,0,0);
      }
    }
    if (hs == 1){
      if (tile < NT-1){
        asm volatile("s_waitcnt vmcnt(0)" ::: "memory");
        __builtin_amdgcn_sched_barrier(0);
        const u32* rw = (const u32*)vreg;
        #pragma unroll
        for (int dl=0; dl<8; ++dl){
          int wi = dl >> 1;
          u32 sel = (dl & 1) ? 0x07060302u : 0x05040100u;
          uint4 o;
          o.x = __builtin_amdgcn_perm(rw[1*4+wi], rw[0*4+wi], sel);
          o.y = __builtin_amdgcn_perm(rw[3*4+wi], rw[2*4+wi], sel);
          o.z = __builtin_amdgcn_perm(rw[5*4+wi], rw[4*4+wi], sel);
          o.w = __builtin_amdgcn_perm(rw[7*4+wi], rw[6*4+wi], sel);
          int d = dblk*8 + dl;
          *(uint4*)(vbuf_n + d*128 + 16*(sblk ^ dl)) = o;
        }
      }
      asm volatile("s_waitcnt lgkmcnt(0)" ::: "memory");
    } else {
      asm volatile("s_waitcnt vmcnt(0) lgkmcnt(0)" ::: "memory");
    }
    __builtin_amdgcn_sched_barrier(0);
    __builtin_amdgcn_s_barrier();
    if (hs == 0 && tile < NT-2){
      #pragma unroll
      for (int r=0;r<8;++r){
        int s = w*16 + 2*r + (lane>>5);
        int slot = (lane & 31) ^ (s & 7);
        gld_lds16(Kg + kbase + (size_t)((tile+2)*BS + s)*Dn + slot*8,
                  (u16*)(smem + (cur ? KB1 : KB0) + (w*16 + 2*r)*512));
      }
    }
    cur ^= 1;
  }
  __syncthreads();
  if (hs == 1){
    char* ob_ = smem + (qg*64 + lane)*256;
    #pragma unroll
    for (int md=0; md<16; ++md)
      *(f32x4*)(ob_ + (md ^ q15)*16) = oa[md];
    *(float*)(smem + VT0 + (qg*64 + lane)*4) = l_run;
  }
  __syncthreads();
  if (hs == 0){
    float lo_ = *(const float*)(smem + VT0 + (qg*64 + lane)*4);
    float inv = 1.f / (l_run + lo_);
    const char* ob_ = smem + (qg*64 + lane)*256;
    const size_t rr = (size_t)(row0 + qg*16 + q15)*Dn + g*4;
    #pragma unroll
    for (int md=0; md<16; ++md){
      f32x4 ob = *(const f32x4*)(ob_ + (md ^ q15)*16);
      float v0 = (oa[md][0] + ob[0])*inv;
      float v1 = (oa[md][1] + ob[1])*inv;
      float v2 = (oa[md][2] + ob[2])*inv;
      float v3 = (oa[md][3] + ob[3])*inv;
      uint2 hi, lo;
      u16 h0=f2bf(v0), h1=f2bf(v1), h2=f2bf(v2), h3=f2bf(v3);
      hi.x = (u32)h0 | ((u32)h1 << 16);
      hi.y = (u32)h2 | ((u32)h3 << 16);
      lo.x = (u32)f2bf(v0 - bf2f(h0)) | ((u32)f2bf(v1 - bf2f(h1)) << 16);
      lo.y = (u32)f2bf(v2 - bf2f(h2)) | ((u32)f2bf(v3 - bf2f(h3)) << 16);
      *(uint2*)(Chi + rr + md*16) = hi;
      *(uint2*)(Clo + rr + md*16) = lo;
    }
  }
}

__global__ void k_finalize(const float* __restrict__ loss3, const float* __restrict__ conf_sum,
                           float* __restrict__ out_scalars){
  if (threadIdx.x == 0){
    float ls = (loss3[0]+loss3[1]+loss3[2]) * (1.f/(3.f*NROWS*Dn));
    float es = 0.f;
    float uniform = 1.f/Tn;
    #pragma unroll
    for (int i=0;i<NTICK*Bn;++i){
      float mean_rm = conf_sum[i] * (1.f/Tn);
      float conf = fminf(fmaxf((mean_rm - uniform)/(1.f - uniform + 1e-6f), 0.f), 1.f);
      es += 2.f + 2.f*conf;
    }
    out_scalars[0] = ls;
    out_scalars[1] = es * (1.f/(NTICK*Bn));
  }
}

extern "C" void kernel_launch(void* const* d_in, const int* in_sizes, int n_in,
                              void* d_out, int out_size, void* d_ws, size_t ws_size,
                              hipStream_t stream) {
  (void)in_sizes; (void)n_in; (void)out_size; (void)ws_size;
  const float* z_in   = (const float*)d_in[0];
  const float* in_w   = (const float*)d_in[1];
  const float* in_b   = (const float*)d_in[2];
  const float* ln_g   = (const float*)d_in[3];
  const float* ln_b   = (const float*)d_in[4];
  const float* q_w    = (const float*)d_in[5];
  const float* q_b    = (const float*)d_in[6];
  const float* k_w    = (const float*)d_in[7];
  const float* k_b    = (const float*)d_in[8];
  const float* v_w    = (const float*)d_in[9];
  const float* v_b    = (const float*)d_in[10];
  const float* o_w    = (const float*)d_in[11];
  const float* o_b    = (const float*)d_in[12];
  const float* log_tau= (const float*)d_in[13];
  const float* p1_w   = (const float*)d_in[14];
  const float* p1_b   = (const float*)d_in[15];
  const float* p2_w   = (const float*)d_in[16];
  const float* p2_b   = (const float*)d_in[17];

  float* out = (float*)d_out;
  const size_t NE = (size_t)NROWS * Dn;   // 4194304

  u16*  zh0  = (u16*)d_ws;
  u16*  zl0  = zh0 + NE;
  u16*  zh1  = zl0 + NE;
  u16*  zl1  = zh1 + NE;
  u16*  hbuf = zl1 + NE;
  u16*  Qb   = hbuf + NE;
  u16*  Kb   = Qb + NE;
  u16*  Vb   = Kb + NE;
  u16*  Chi  = Vb + NE;
  u16*  Clo  = Chi + NE;
  u16*  t1b  = Clo + NE;
  u16*  wbf  = t1b + NE;                // 14 x [256][256] bf16 (7 hi, 7 lo)
  float* stats = (float*)(wbf + 14*WP);
  float* conf_sum = stats;        // [3][8]
  float* loss     = stats + 24;   // [3]
  float* mrowb    = stats + 64;   // [16384] per-row sim-max (reused per tick)

  k_prep<<<dim3(64,7), 256, 0, stream>>>(in_w, q_w, k_w, v_w, o_w, p1_w, p2_w, wbf);
  k_split<<<4096, 256, 0, stream>>>(z_in, zh0, zl0, stats);

  u16* zh_list[2] = { zh0, zh1 };
  u16* zl_list[2] = { zl0, zl1 };

  for (int t = 0; t < NTICK; ++t){
    u16* zh_old = zh_list[t & 1];
    u16* zl_old = zl_list[t & 1];
    u16* zh_new = zh_list[(t+1) & 1];
    u16* zl_new = zl_list[(t+1) & 1];
    float* zout = (t == NTICK-1) ? out : nullptr;
    k_gemm_ln<<<NBLKG, 256, 0, stream>>>(zh_old, zl_old, wbf + 0*WP, wbf + 7*WP,
                                         in_b, ln_g, ln_b, hbuf);
    k_gemm_qkv<<<dim3(NBLKG,3), 256, 0, stream>>>(hbuf, wbf, q_b, k_b, v_b, Qb, Kb, Vb);
    k_passA<<<NBLKA, 256, 0, stream>>>(Qb, Kb, conf_sum + t*8, mrowb);
    k_passB<<<NBLKA, 512, 0, stream>>>(Qb, Kb, Vb, conf_sum + t*8, mrowb, Chi, Clo);
    k_gemm_update<<<NBLKG, 256, 0, stream>>>(Chi, Clo, wbf + 4*WP, wbf + 11*WP, o_b,
                                             zh_old, zl_old, log_tau, zh_new, zl_new, zout);
    k_gemm_relu<<<NBLKG, 256, 0, stream>>>(zh_old, wbf + 5*WP, p1_b, t1b);
    k_gemm_loss<<<NBLKG, 256, 0, stream>>>(t1b, wbf + 6*WP, p2_b, zh_new, zl_new, loss + t);
  }
  k_finalize<<<1, 64, 0, stream>>>(loss, conf_sum, out + NE);
}